// Round 1
// baseline (1375.569 us; speedup 1.0000x reference)
//
#include <hip/hip_runtime.h>

typedef __attribute__((ext_vector_type(8))) short short8;
typedef __attribute__((ext_vector_type(4))) short short4v;
typedef __attribute__((ext_vector_type(4))) float float4v;

#define N_EDGES 640000

// RNE float -> bf16 (as raw short)
__device__ __forceinline__ short f2bf(float f) {
  union { float f; unsigned u; } a; a.f = f;
  unsigned r = a.u + 0x7FFFu + ((a.u >> 16) & 1u);
  return (short)(r >> 16);
}

__device__ __forceinline__ float fast_tanh(float x) {
  float xc = fminf(fmaxf(x, -15.f), 15.f);
  float e = __expf(2.f * xc);                       // v_exp_f32 path
  return (e - 1.f) * __builtin_amdgcn_rcpf(e + 1.f);
}

// Convert the 5 weight matrices to bf16 into ws.
// Layout (shorts): U[0..16384) V[16384..32768) P[32768..49152)
//                  W1[49152..81920) W2[81920..98304)
__global__ void prep_kernel(const float* __restrict__ U_w, const float* __restrict__ V_w,
                            const float* __restrict__ P_w, const float* __restrict__ W1,
                            const float* __restrict__ W2, short* __restrict__ ws) {
  int i = blockIdx.x * 256 + threadIdx.x;
  if (i >= 98304) return;
  float v;
  if (i < 16384)       v = U_w[i];
  else if (i < 32768)  v = V_w[i - 16384];
  else if (i < 49152)  v = P_w[i - 32768];
  else if (i < 81920)  v = W1[i - 49152];
  else                 v = W2[i - 81920];
  ws[i] = f2bf(v);
}

// One wave owns 16 edges through the whole pipeline. No cross-wave deps.
__global__ __launch_bounds__(256, 2) void fused_kernel(
    const float* __restrict__ V, const float* __restrict__ E,
    const int* __restrict__ src, const int* __restrict__ dst,
    const short* __restrict__ wbf,
    const float* __restrict__ Pb, const float* __restrict__ b1,
    const float* __restrict__ b2, float* __restrict__ out) {
  // per-wave buffers: [wave][buf][row][128+8 pad]  (pad -> 2-way bank alias = free)
  __shared__ short lds[4][3][16][136];
  const int wave = threadIdx.x >> 6;
  const int lane = threadIdx.x & 63;
  const int l15  = lane & 15;
  const int quad = lane >> 4;
  const int eb   = blockIdx.x * 64 + wave * 16;   // this wave's first edge

  short (*bufS)[136] = lds[wave][0];  // Vsrc -> t -> h1
  short (*bufD)[136] = lds[wave][1];  // Vdst -> pooled
  short (*bufE)[136] = lds[wave][2];  // leakyrelu(E)

  const short* wU  = wbf;
  const short* wV  = wbf + 16384;
  const short* wP  = wbf + 32768;
  const short* wW1 = wbf + 49152;   // [128][256]
  const short* wW2 = wbf + 81920;

  // ---------- staging: gather V[src], V[dst], leaky(E) -> LDS bf16 ----------
  for (int i = lane; i < 512; i += 64) {     // 16 rows * 32 float4-chunks
    int row = i >> 5;
    int ch  = i & 31;
    int e   = eb + row;
    int s = src[e], d = dst[e];
    float4v vs = *((const float4v*)(V + (size_t)s * 128) + ch);
    float4v vd = *((const float4v*)(V + (size_t)d * 128) + ch);
    float4v ve = *((const float4v*)(E + (size_t)e * 128) + ch);
    short4v ps = {f2bf(vs[0]), f2bf(vs[1]), f2bf(vs[2]), f2bf(vs[3])};
    short4v pd = {f2bf(vd[0]), f2bf(vd[1]), f2bf(vd[2]), f2bf(vd[3])};
    float e0 = ve[0] > 0.f ? ve[0] : 0.01f * ve[0];
    float e1 = ve[1] > 0.f ? ve[1] : 0.01f * ve[1];
    float e2 = ve[2] > 0.f ? ve[2] : 0.01f * ve[2];
    float e3 = ve[3] > 0.f ? ve[3] : 0.01f * ve[3];
    short4v pe = {f2bf(e0), f2bf(e1), f2bf(e2), f2bf(e3)};
    *(short4v*)&bufS[row][ch * 4] = ps;
    *(short4v*)&bufD[row][ch * 4] = pd;
    *(short4v*)&bufE[row][ch * 4] = pe;
  }
  asm volatile("s_waitcnt lgkmcnt(0)" ::: "memory");

  // ---------- stage 1: h_s = Vs @ U^T, h_d = Vd @ Vw^T ----------
  float4v accS[8], accD[8];
#pragma unroll
  for (int n = 0; n < 8; n++) { accS[n] = (float4v){0.f,0.f,0.f,0.f}; accD[n] = (float4v){0.f,0.f,0.f,0.f}; }
#pragma unroll
  for (int kk = 0; kk < 4; kk++) {
    short8 aS = *(const short8*)&bufS[l15][kk * 32 + quad * 8];
    short8 aD = *(const short8*)&bufD[l15][kk * 32 + quad * 8];
#pragma unroll
    for (int n = 0; n < 8; n++) {
      short8 bU = *(const short8*)(wU + (n * 16 + l15) * 128 + kk * 32 + quad * 8);
      short8 bV = *(const short8*)(wV + (n * 16 + l15) * 128 + kk * 32 + quad * 8);
      accS[n] = __builtin_amdgcn_mfma_f32_16x16x32_bf16(aS, bU, accS[n], 0, 0, 0);
      accD[n] = __builtin_amdgcn_mfma_f32_16x16x32_bf16(aD, bV, accD[n], 0, 0, 0);
    }
  }
  // t = tanh(h_s * h_d) -> bufS (this wave's reads of bufS are complete; DS in-order)
#pragma unroll
  for (int n = 0; n < 8; n++)
#pragma unroll
    for (int r = 0; r < 4; r++) {
      float t = fast_tanh(accS[n][r] * accD[n][r]);
      bufS[quad * 4 + r][n * 16 + l15] = f2bf(t);
    }
  asm volatile("s_waitcnt lgkmcnt(0)" ::: "memory");

  // ---------- stage 2: pooled = t @ P^T + Pb -> bufD ----------
  float4v acc[8];
#pragma unroll
  for (int n = 0; n < 8; n++) acc[n] = (float4v){0.f,0.f,0.f,0.f};
#pragma unroll
  for (int kk = 0; kk < 4; kk++) {
    short8 a = *(const short8*)&bufS[l15][kk * 32 + quad * 8];
#pragma unroll
    for (int n = 0; n < 8; n++) {
      short8 b = *(const short8*)(wP + (n * 16 + l15) * 128 + kk * 32 + quad * 8);
      acc[n] = __builtin_amdgcn_mfma_f32_16x16x32_bf16(a, b, acc[n], 0, 0, 0);
    }
  }
#pragma unroll
  for (int n = 0; n < 8; n++) {
    float bias = Pb[n * 16 + l15];
#pragma unroll
    for (int r = 0; r < 4; r++)
      bufD[quad * 4 + r][n * 16 + l15] = f2bf(acc[n][r] + bias);
  }
  asm volatile("s_waitcnt lgkmcnt(0)" ::: "memory");

  // ---------- stage 3: h1 = relu(pooled @ W1a^T + Ea @ W1b^T + b1) -> bufS ----------
#pragma unroll
  for (int n = 0; n < 8; n++) acc[n] = (float4v){0.f,0.f,0.f,0.f};
#pragma unroll
  for (int kk = 0; kk < 4; kk++) {
    short8 a = *(const short8*)&bufD[l15][kk * 32 + quad * 8];
#pragma unroll
    for (int n = 0; n < 8; n++) {
      short8 b = *(const short8*)(wW1 + (n * 16 + l15) * 256 + kk * 32 + quad * 8);
      acc[n] = __builtin_amdgcn_mfma_f32_16x16x32_bf16(a, b, acc[n], 0, 0, 0);
    }
  }
#pragma unroll
  for (int kk = 0; kk < 4; kk++) {
    short8 a = *(const short8*)&bufE[l15][kk * 32 + quad * 8];
#pragma unroll
    for (int n = 0; n < 8; n++) {
      short8 b = *(const short8*)(wW1 + (n * 16 + l15) * 256 + 128 + kk * 32 + quad * 8);
      acc[n] = __builtin_amdgcn_mfma_f32_16x16x32_bf16(a, b, acc[n], 0, 0, 0);
    }
  }
#pragma unroll
  for (int n = 0; n < 8; n++) {
    float bias = b1[n * 16 + l15];
#pragma unroll
    for (int r = 0; r < 4; r++) {
      float v = fmaxf(acc[n][r] + bias, 0.f);
      bufS[quad * 4 + r][n * 16 + l15] = f2bf(v);
    }
  }
  asm volatile("s_waitcnt lgkmcnt(0)" ::: "memory");

  // ---------- stage 4: out = relu(h1 @ W2^T + b2) -> global ----------
#pragma unroll
  for (int n = 0; n < 8; n++) acc[n] = (float4v){0.f,0.f,0.f,0.f};
#pragma unroll
  for (int kk = 0; kk < 4; kk++) {
    short8 a = *(const short8*)&bufS[l15][kk * 32 + quad * 8];
#pragma unroll
    for (int n = 0; n < 8; n++) {
      short8 b = *(const short8*)(wW2 + (n * 16 + l15) * 128 + kk * 32 + quad * 8);
      acc[n] = __builtin_amdgcn_mfma_f32_16x16x32_bf16(a, b, acc[n], 0, 0, 0);
    }
  }
#pragma unroll
  for (int n = 0; n < 8; n++) {
    float bias = b2[n * 16 + l15];
#pragma unroll
    for (int r = 0; r < 4; r++) {
      float v = fmaxf(acc[n][r] + bias, 0.f);
      out[(size_t)(eb + quad * 4 + r) * 128 + n * 16 + l15] = v;
    }
  }
}

extern "C" void kernel_launch(void* const* d_in, const int* in_sizes, int n_in,
                              void* d_out, int out_size, void* d_ws, size_t ws_size,
                              hipStream_t stream) {
  const float* V   = (const float*)d_in[0];
  const float* E   = (const float*)d_in[1];
  const int*   src = (const int*)d_in[2];
  const int*   dst = (const int*)d_in[3];
  const float* U_w = (const float*)d_in[4];
  const float* V_w = (const float*)d_in[5];
  const float* P_w = (const float*)d_in[6];
  const float* P_b = (const float*)d_in[7];
  const float* W1  = (const float*)d_in[8];
  const float* b1  = (const float*)d_in[9];
  const float* W2  = (const float*)d_in[10];
  const float* b2  = (const float*)d_in[11];
  short* ws = (short*)d_ws;

  hipLaunchKernelGGL(prep_kernel, dim3(384), dim3(256), 0, stream,
                     U_w, V_w, P_w, W1, W2, ws);
  hipLaunchKernelGGL(fused_kernel, dim3(N_EDGES / 64), dim3(256), 0, stream,
                     V, E, src, dst, ws, P_b, b1, b2, (float*)d_out);
}

// Round 2
// 828.208 us; speedup vs baseline: 1.6609x; 1.6609x over previous
//
#include <hip/hip_runtime.h>

typedef __attribute__((ext_vector_type(8))) short short8;
typedef __attribute__((ext_vector_type(4))) short short4v;
typedef __attribute__((ext_vector_type(4))) float float4v;

#define N_EDGES 640000

// RNE float -> bf16 (as raw short)
__device__ __forceinline__ short f2bf(float f) {
  union { float f; unsigned u; } a; a.f = f;
  unsigned r = a.u + 0x7FFFu + ((a.u >> 16) & 1u);
  return (short)(r >> 16);
}

__device__ __forceinline__ float fast_tanh(float x) {
  float xc = fminf(fmaxf(x, -15.f), 15.f);
  float e = __expf(2.f * xc);
  return (e - 1.f) * __builtin_amdgcn_rcpf(e + 1.f);
}

// Convert the 5 weight matrices to bf16 into ws.
// Layout (shorts): U[0..16384) V[16384..32768) P[32768..49152)
//                  W1[49152..81920) W2[81920..98304)
__global__ void prep_kernel(const float* __restrict__ U_w, const float* __restrict__ V_w,
                            const float* __restrict__ P_w, const float* __restrict__ W1,
                            const float* __restrict__ W2, short* __restrict__ ws) {
  int i = blockIdx.x * 256 + threadIdx.x;
  if (i >= 98304) return;
  float v;
  if (i < 16384)       v = U_w[i];
  else if (i < 32768)  v = V_w[i - 16384];
  else if (i < 49152)  v = P_w[i - 32768];
  else if (i < 81920)  v = W1[i - 49152];
  else                 v = W2[i - 81920];
  ws[i] = f2bf(v);
}

// Block = 64 edges in shared LDS. 4 waves split the N dimension (2 n-tiles each).
// B-fragments loaded once per stage per wave, reused across 4 m-tiles.
__global__ __launch_bounds__(256, 3) void fused_kernel(
    const float* __restrict__ V, const float* __restrict__ E,
    const int* __restrict__ src, const int* __restrict__ dst,
    const short* __restrict__ wbf,
    const float* __restrict__ Pb, const float* __restrict__ b1,
    const float* __restrict__ b2, float* __restrict__ out) {
  __shared__ short bufA[64][136];  // Vsrc -> t -> h1
  __shared__ short bufB[64][136];  // Vdst -> pooled
  __shared__ short bufE[64][136];  // leakyrelu(E)

  const int tid  = threadIdx.x;
  const int lane = tid & 63;
  const int wave = tid >> 6;
  const int l15  = lane & 15;
  const int quad = lane >> 4;
  const int eb   = blockIdx.x * 64;
  const int n0   = wave * 2;            // this wave's first n-tile

  const short* wU  = wbf;
  const short* wV  = wbf + 16384;
  const short* wP  = wbf + 32768;
  const short* wW1 = wbf + 49152;   // [128][256]
  const short* wW2 = wbf + 81920;

  // biases for this wave's output columns
  float pb[2], b1v[2], b2v[2];
#pragma unroll
  for (int n = 0; n < 2; n++) {
    int c = (n0 + n) * 16 + l15;
    pb[n] = Pb[c]; b1v[n] = b1[c]; b2v[n] = b2[c];
  }

  // ---------- staging: gather V[src], V[dst], leaky(E) -> LDS bf16 ----------
  for (int i = tid; i < 2048; i += 256) {   // 64 rows * 32 float4-chunks
    int row = i >> 5;
    int ch  = i & 31;
    int e   = eb + row;
    int s = src[e], d = dst[e];
    float4v vs = *((const float4v*)(V + (size_t)s * 128) + ch);
    float4v vd = *((const float4v*)(V + (size_t)d * 128) + ch);
    float4v ve = __builtin_nontemporal_load((const float4v*)(E + (size_t)e * 128) + ch);
    short4v ps = {f2bf(vs[0]), f2bf(vs[1]), f2bf(vs[2]), f2bf(vs[3])};
    short4v pd = {f2bf(vd[0]), f2bf(vd[1]), f2bf(vd[2]), f2bf(vd[3])};
    float e0 = ve[0] > 0.f ? ve[0] : 0.01f * ve[0];
    float e1 = ve[1] > 0.f ? ve[1] : 0.01f * ve[1];
    float e2 = ve[2] > 0.f ? ve[2] : 0.01f * ve[2];
    float e3 = ve[3] > 0.f ? ve[3] : 0.01f * ve[3];
    short4v pe = {f2bf(e0), f2bf(e1), f2bf(e2), f2bf(e3)};
    *(short4v*)&bufA[row][ch * 4] = ps;
    *(short4v*)&bufB[row][ch * 4] = pd;
    *(short4v*)&bufE[row][ch * 4] = pe;
  }
  __syncthreads();

  // ---------- stage 1: h_s = Vs @ U^T, h_d = Vd @ Vw^T (acc held in regs) ----------
  {
    short8 bU[2][4], bV[2][4];
#pragma unroll
    for (int n = 0; n < 2; n++)
#pragma unroll
      for (int kk = 0; kk < 4; kk++) {
        const int off = ((n0 + n) * 16 + l15) * 128 + kk * 32 + quad * 8;
        bU[n][kk] = *(const short8*)(wU + off);
        bV[n][kk] = *(const short8*)(wV + off);
      }
    float4v accS[4][2], accD[4][2];
#pragma unroll
    for (int m = 0; m < 4; m++)
#pragma unroll
      for (int n = 0; n < 2; n++) {
        accS[m][n] = (float4v){0.f, 0.f, 0.f, 0.f};
        accD[m][n] = (float4v){0.f, 0.f, 0.f, 0.f};
      }
#pragma unroll
    for (int m = 0; m < 4; m++)
#pragma unroll
      for (int kk = 0; kk < 4; kk++) {
        short8 aS = *(const short8*)&bufA[m * 16 + l15][kk * 32 + quad * 8];
        short8 aD = *(const short8*)&bufB[m * 16 + l15][kk * 32 + quad * 8];
#pragma unroll
        for (int n = 0; n < 2; n++) {
          accS[m][n] = __builtin_amdgcn_mfma_f32_16x16x32_bf16(aS, bU[n][kk], accS[m][n], 0, 0, 0);
          accD[m][n] = __builtin_amdgcn_mfma_f32_16x16x32_bf16(aD, bV[n][kk], accD[m][n], 0, 0, 0);
        }
      }
    __syncthreads();   // all stage-1 LDS reads done; safe to overwrite bufA
    // t = tanh(h_s * h_d) -> bufA
#pragma unroll
    for (int m = 0; m < 4; m++)
#pragma unroll
      for (int n = 0; n < 2; n++)
#pragma unroll
        for (int r = 0; r < 4; r++) {
          float t = fast_tanh(accS[m][n][r] * accD[m][n][r]);
          bufA[m * 16 + quad * 4 + r][(n0 + n) * 16 + l15] = f2bf(t);
        }
  }
  __syncthreads();

  // ---------- stage 2: pooled = t @ P^T + Pb -> bufB ----------
  {
    short8 bP[2][4];
#pragma unroll
    for (int n = 0; n < 2; n++)
#pragma unroll
      for (int kk = 0; kk < 4; kk++)
        bP[n][kk] = *(const short8*)(wP + ((n0 + n) * 16 + l15) * 128 + kk * 32 + quad * 8);
#pragma unroll
    for (int m = 0; m < 4; m++) {
      float4v acc[2] = {(float4v){0.f,0.f,0.f,0.f}, (float4v){0.f,0.f,0.f,0.f}};
#pragma unroll
      for (int kk = 0; kk < 4; kk++) {
        short8 a = *(const short8*)&bufA[m * 16 + l15][kk * 32 + quad * 8];
#pragma unroll
        for (int n = 0; n < 2; n++)
          acc[n] = __builtin_amdgcn_mfma_f32_16x16x32_bf16(a, bP[n][kk], acc[n], 0, 0, 0);
      }
#pragma unroll
      for (int n = 0; n < 2; n++)
#pragma unroll
        for (int r = 0; r < 4; r++)
          bufB[m * 16 + quad * 4 + r][(n0 + n) * 16 + l15] = f2bf(acc[n][r] + pb[n]);
    }
  }
  __syncthreads();

  // ---------- stage 3: h1 = relu([pooled, Ea] @ W1^T + b1) -> bufA ----------
  {
    short8 bW[2][8];
#pragma unroll
    for (int n = 0; n < 2; n++) {
      const int rowoff = ((n0 + n) * 16 + l15) * 256;
#pragma unroll
      for (int kk = 0; kk < 4; kk++) {
        bW[n][kk]     = *(const short8*)(wW1 + rowoff + kk * 32 + quad * 8);
        bW[n][kk + 4] = *(const short8*)(wW1 + rowoff + 128 + kk * 32 + quad * 8);
      }
    }
#pragma unroll
    for (int m = 0; m < 4; m++) {
      float4v acc[2] = {(float4v){0.f,0.f,0.f,0.f}, (float4v){0.f,0.f,0.f,0.f}};
#pragma unroll
      for (int kk = 0; kk < 4; kk++) {
        short8 a = *(const short8*)&bufB[m * 16 + l15][kk * 32 + quad * 8];
#pragma unroll
        for (int n = 0; n < 2; n++)
          acc[n] = __builtin_amdgcn_mfma_f32_16x16x32_bf16(a, bW[n][kk], acc[n], 0, 0, 0);
      }
#pragma unroll
      for (int kk = 0; kk < 4; kk++) {
        short8 a = *(const short8*)&bufE[m * 16 + l15][kk * 32 + quad * 8];
#pragma unroll
        for (int n = 0; n < 2; n++)
          acc[n] = __builtin_amdgcn_mfma_f32_16x16x32_bf16(a, bW[n][kk + 4], acc[n], 0, 0, 0);
      }
#pragma unroll
      for (int n = 0; n < 2; n++)
#pragma unroll
        for (int r = 0; r < 4; r++) {
          float v = fmaxf(acc[n][r] + b1v[n], 0.f);
          bufA[m * 16 + quad * 4 + r][(n0 + n) * 16 + l15] = f2bf(v);
        }
    }
  }
  __syncthreads();

  // ---------- stage 4: out = relu(h1 @ W2^T + b2) -> global ----------
  {
    short8 bW[2][4];
#pragma unroll
    for (int n = 0; n < 2; n++)
#pragma unroll
      for (int kk = 0; kk < 4; kk++)
        bW[n][kk] = *(const short8*)(wW2 + ((n0 + n) * 16 + l15) * 128 + kk * 32 + quad * 8);
#pragma unroll
    for (int m = 0; m < 4; m++) {
      float4v acc[2] = {(float4v){0.f,0.f,0.f,0.f}, (float4v){0.f,0.f,0.f,0.f}};
#pragma unroll
      for (int kk = 0; kk < 4; kk++) {
        short8 a = *(const short8*)&bufA[m * 16 + l15][kk * 32 + quad * 8];
#pragma unroll
        for (int n = 0; n < 2; n++)
          acc[n] = __builtin_amdgcn_mfma_f32_16x16x32_bf16(a, bW[n][kk], acc[n], 0, 0, 0);
      }
#pragma unroll
      for (int n = 0; n < 2; n++)
#pragma unroll
        for (int r = 0; r < 4; r++) {
          float v = fmaxf(acc[n][r] + b2v[n], 0.f);
          __builtin_nontemporal_store(
              v, out + (size_t)(eb + m * 16 + quad * 4 + r) * 128 + (n0 + n) * 16 + l15);
        }
    }
  }
}

extern "C" void kernel_launch(void* const* d_in, const int* in_sizes, int n_in,
                              void* d_out, int out_size, void* d_ws, size_t ws_size,
                              hipStream_t stream) {
  const float* V   = (const float*)d_in[0];
  const float* E   = (const float*)d_in[1];
  const int*   src = (const int*)d_in[2];
  const int*   dst = (const int*)d_in[3];
  const float* U_w = (const float*)d_in[4];
  const float* V_w = (const float*)d_in[5];
  const float* P_w = (const float*)d_in[6];
  const float* P_b = (const float*)d_in[7];
  const float* W1  = (const float*)d_in[8];
  const float* b1  = (const float*)d_in[9];
  const float* W2  = (const float*)d_in[10];
  const float* b2  = (const float*)d_in[11];
  short* ws = (short*)d_ws;

  hipLaunchKernelGGL(prep_kernel, dim3(384), dim3(256), 0, stream,
                     U_w, V_w, P_w, W1, W2, ws);
  hipLaunchKernelGGL(fused_kernel, dim3(N_EDGES / 64), dim3(256), 0, stream,
                     V, E, src, dst, ws, P_b, b1, b2, (float*)d_out);
}